// Round 9
// baseline (473.127 us; speedup 1.0000x reference)
//
#include <hip/hip_runtime.h>

#define NN 100000
#define NE 800000
#define NG 128
#define U  128
#define NGIN 3
#define NBUCK 64
#define NPB 1563                 // ceil(NN / NBUCK)
#define ACHUNK 4096
#define NAB ((NE + ACHUNK - 1) / ACHUNK)   // 196 phase-A blocks

typedef short bf16x8 __attribute__((ext_vector_type(8)));
typedef float f32x4 __attribute__((ext_vector_type(4)));

__device__ __forceinline__ unsigned short f2b(float f) {
    union { float f; unsigned u; } v; v.f = f;
    unsigned r = v.u + 0x7FFF + ((v.u >> 16) & 1);   // RNE
    return (unsigned short)(r >> 16);
}
__device__ __forceinline__ float blo(unsigned u) {
    union { unsigned u; float f; } v; v.u = u << 16; return v.f;
}
__device__ __forceinline__ float bhi(unsigned u) {
    union { unsigned u; float f; } v; v.u = u & 0xffff0000u; return v.f;
}
__device__ __forceinline__ unsigned cvtpk(float lo, float hi) {
    unsigned r;
    asm("v_cvt_pk_bf16_f32 %0, %1, %2" : "=v"(r) : "v"(lo), "v"(hi));
    return r;
}

// ---------------------------------------------------------------------------
// x (fp32) -> hb (bf16)
// ---------------------------------------------------------------------------
__global__ __launch_bounds__(256) void convert_k(const float* __restrict__ x,
                                                 unsigned short* __restrict__ hb) {
    int i = blockIdx.x * 256 + threadIdx.x;
    if (i >= NN * U / 4) return;
    float4 v = reinterpret_cast<const float4*>(x)[i];
    uint2 o;
    o.x = (unsigned)f2b(v.x) | ((unsigned)f2b(v.y) << 16);
    o.y = (unsigned)f2b(v.z) | ((unsigned)f2b(v.w) << 16);
    reinterpret_cast<uint2*>(hb)[i] = o;
}

// ---------------------------------------------------------------------------
// pack W (fp32 [k][c]) into MFMA fragment order (bf16):
// frag[((t*4+ks)*64+lane)*8+j] = W[ks*32+8*(lane>>4)+j][t*16+(lane&15)]
// (serves as B-frag of W, and identically as A-frag of W^T)
// ---------------------------------------------------------------------------
__global__ __launch_bounds__(256) void wfrag_k(const float* __restrict__ W1,
                                               const float* __restrict__ W2,
                                               unsigned short* __restrict__ wfrag) {
    int b = blockIdx.x;
    const float* src = ((b & 1) ? W2 : W1) + (size_t)(b >> 1) * U * U;
    unsigned short* dst = wfrag + (size_t)b * 16384;
    for (int e = threadIdx.x; e < 16384; e += 256) {
        int j = e & 7, lane = (e >> 3) & 63, ks = (e >> 9) & 3, ct = e >> 11;
        int k = ks * 32 + ((lane >> 4) << 3) + j;
        int c = ct * 16 + (lane & 15);
        dst[e] = f2b(src[k * U + c]);
    }
}

// ---------------------------------------------------------------------------
// CSR build, owner-computes (bhist -> bscan -> phaseA -> phaseB)
// ---------------------------------------------------------------------------
__global__ __launch_bounds__(256) void bhist_k(const int* __restrict__ ei,
                                               int* __restrict__ bcnt) {
    __shared__ int lh[NBUCK];
    int tid = threadIdx.x;
    if (tid < NBUCK) lh[tid] = 0;
    __syncthreads();
    int e0 = blockIdx.x * ACHUNK;
    int eend = min(e0 + ACHUNK, NE);
    for (int e = e0 + tid; e < eend; e += 256)
        atomicAdd(&lh[ei[e] / NPB], 1);
    __syncthreads();
    if (tid < NBUCK && lh[tid]) atomicAdd(&bcnt[tid], lh[tid]);
}

__global__ __launch_bounds__(64) void bscan_k(const int* __restrict__ bcnt,
                                              int* __restrict__ bcur,
                                              int* __restrict__ boff,
                                              int* __restrict__ rowptr) {
    int lane = threadIdx.x;
    int v = bcnt[lane];
    int incl = v;
#pragma unroll
    for (int off = 1; off < 64; off <<= 1) {
        int n = __shfl_up(incl, off);
        if (lane >= off) incl += n;
    }
    int excl = incl - v;
    bcur[lane] = excl;
    boff[lane] = excl;
    if (lane == 63) { boff[64] = incl; rowptr[NN] = NE; }
}

__global__ __launch_bounds__(256) void phaseA_k(const int* __restrict__ ei,
                                                const float* __restrict__ ew,
                                                int* __restrict__ bcur,
                                                uint2* __restrict__ tmp) {
    __shared__ int lh[NBUCK];
    int tid = threadIdx.x;
    if (tid < NBUCK) lh[tid] = 0;
    __syncthreads();
    int e0 = blockIdx.x * ACHUNK;
    int eend = min(e0 + ACHUNK, NE);
    for (int e = e0 + tid; e < eend; e += 256)
        atomicAdd(&lh[ei[e] / NPB], 1);
    __syncthreads();
    if (tid < NBUCK) {
        int c = lh[tid];
        lh[tid] = c ? atomicAdd(&bcur[tid], c) : 0;
    }
    __syncthreads();
    for (int e = e0 + tid; e < eend; e += 256) {
        int d = ei[e];
        int pos = atomicAdd(&lh[d / NPB], 1);
        uint2 r;
        r.x = ((unsigned)ei[NE + e] << 15) | (unsigned)f2b(ew[e]);
        r.y = (unsigned)d;
        tmp[pos] = r;
    }
}

__global__ __launch_bounds__(256) void phaseB_k(const uint2* __restrict__ tmp,
                                                const int* __restrict__ boff,
                                                int* __restrict__ rowptr,
                                                unsigned* __restrict__ esw) {
    __shared__ int cnt[1792];
    __shared__ int ws[4];
    const int tid = threadIdx.x;
    const int b = blockIdx.x;
    const int n0 = b * NPB;
    const int npb = min(NPB, NN - n0);
    const int wbeg = boff[b], wend = boff[b + 1];

    for (int i = tid; i < 1792; i += 256) cnt[i] = 0;
    __syncthreads();
    for (int e = wbeg + tid; e < wend; e += 256)
        atomicAdd(&cnt[(int)tmp[e].y - n0], 1);
    __syncthreads();
    int base = tid * 7;
    int v[7]; int s = 0;
#pragma unroll
    for (int k = 0; k < 7; ++k) { v[k] = cnt[base + k]; s += v[k]; }
    int lane = tid & 63, wid = tid >> 6;
    int incl = s;
#pragma unroll
    for (int off = 1; off < 64; off <<= 1) {
        int n = __shfl_up(incl, off);
        if (lane >= off) incl += n;
    }
    if (lane == 63) ws[wid] = incl;
    __syncthreads();
    if (tid == 0) {
        int a = 0;
#pragma unroll
        for (int w = 0; w < 4; ++w) { int t = ws[w]; ws[w] = a; a += t; }
    }
    __syncthreads();
    int run = wbeg + ws[wid] + (incl - s);
#pragma unroll
    for (int k = 0; k < 7; ++k) { cnt[base + k] = run; run += v[k]; }
    __syncthreads();
    for (int i = tid; i < npb; i += 256) rowptr[n0 + i] = cnt[i];
    __syncthreads();
    for (int e = wbeg + tid; e < wend; e += 256) {
        uint2 r = tmp[e];
        int pos = atomicAdd(&cnt[(int)r.y - n0], 1);
        esw[pos] = r.x;
    }
}

// ---------------------------------------------------------------------------
// gather: z[n] = 1.5*h[n] + sum h[src]*w ; unroll x8, 8 row loads in flight
// ---------------------------------------------------------------------------
__global__ __launch_bounds__(256) void gather_k(const unsigned short* __restrict__ h,
                                                const unsigned* __restrict__ esw,
                                                const int* __restrict__ rowptr,
                                                unsigned short* __restrict__ z) {
    int node = blockIdx.x * 4 + (threadIdx.x >> 6);
    if (node >= NN) return;
    int lane = threadIdx.x & 63;
    const unsigned* hp = reinterpret_cast<const unsigned*>(h);
    int beg = rowptr[node], end = rowptr[node + 1];

    float ax[8], ay[8];
#pragma unroll
    for (int k = 0; k < 8; ++k) { ax[k] = 0.f; ay[k] = 0.f; }

    for (int cb = beg; cb < end; cb += 64) {
        int n = min(end - cb, 64);
        unsigned rec = (lane < n) ? esw[cb + lane] : 0u;   // pad: src 0, w +0.0
        int sv = (int)(rec >> 15);
        float wv = __uint_as_float((rec & 0x7FFFu) << 16);
        for (int i = 0; i < n; i += 8) {
            int s_[8]; float w_[8]; unsigned h_[8];
#pragma unroll
            for (int k = 0; k < 8; ++k) {
                s_[k] = __shfl(sv, i + k);
                w_[k] = __shfl(wv, i + k);
            }
#pragma unroll
            for (int k = 0; k < 8; ++k)
                h_[k] = hp[(size_t)s_[k] * 64 + lane];
#pragma unroll
            for (int k = 0; k < 8; ++k) {
                ax[k] = fmaf(blo(h_[k]), w_[k], ax[k]);
                ay[k] = fmaf(bhi(h_[k]), w_[k], ay[k]);
            }
        }
    }
    float axs = ((ax[0] + ax[1]) + (ax[2] + ax[3])) + ((ax[4] + ax[5]) + (ax[6] + ax[7]));
    float ays = ((ay[0] + ay[1]) + (ay[2] + ay[3])) + ((ay[4] + ay[5]) + (ay[6] + ay[7]));
    unsigned hn = hp[(size_t)node * 64 + lane];
    axs = fmaf(1.5f, blo(hn), axs);
    ays = fmaf(1.5f, bhi(hn), ays);
    reinterpret_cast<unsigned*>(z)[(size_t)node * 64 + lane] =
        (unsigned)f2b(axs) | ((unsigned)f2b(ays) << 16);
}

// ---------------------------------------------------------------------------
// fused dense, swapped-operand form (no LDS, no barrier):
//   z1^T = W1^T @ z^T  (A = wfrag(W1), B = z rows as b128)
//   register transpose of z1 C/D-frags -> B-frags (cvt_pk + shfl)
//   h^T  = W2^T @ z1^T
// lane (r = lane&15, hi = lane>>4) holds per strip: node-row r0+r,
// cols {mt*16 + hi*4 + j}. Two 16-row strips per wave.
// ---------------------------------------------------------------------------
__global__ __launch_bounds__(256) void fused_dense_k(const unsigned short* __restrict__ z,
                                                     const unsigned short* __restrict__ wf1,
                                                     const unsigned short* __restrict__ wf2,
                                                     const float* __restrict__ bias1,
                                                     const float* __restrict__ bias2,
                                                     const float* __restrict__ gamma,
                                                     const float* __restrict__ beta,
                                                     const float* __restrict__ mean,
                                                     const float* __restrict__ var,
                                                     const int* __restrict__ gidx,
                                                     unsigned short* __restrict__ outp,
                                                     float* __restrict__ pooled,
                                                     int pool_off) {
    const int lane = threadIdx.x & 63;
    const int wid = threadIdx.x >> 6;
    const int r = lane & 15;
    const int hi = lane >> 4;
    const int strip0 = blockIdx.x * 8 + wid * 2;

    bool valid[2]; int rs[2];
#pragma unroll
    for (int s = 0; s < 2; ++s) {
        int st = strip0 + s;
        valid[s] = (st * 16 < NN);
        rs[s] = valid[s] ? st * 16 : 0;
    }

    // B-frags of z^T: lane holds z[rs+r][ks*32 + hi*8 .. +8]
    bf16x8 zf[2][4];
#pragma unroll
    for (int s = 0; s < 2; ++s) {
        const size_t zb = (size_t)(rs[s] + r) * U + (hi << 3);
#pragma unroll
        for (int ks = 0; ks < 4; ++ks)
            zf[s][ks] = *reinterpret_cast<const bf16x8*>(z + zb + ks * 32);
    }

    // matmul 1
    f32x4 acc1[2][8];
#pragma unroll
    for (int s = 0; s < 2; ++s)
#pragma unroll
        for (int mt = 0; mt < 8; ++mt) acc1[s][mt] = (f32x4){0.f, 0.f, 0.f, 0.f};
#pragma unroll
    for (int mt = 0; mt < 8; ++mt)
#pragma unroll
        for (int ks = 0; ks < 4; ++ks) {
            bf16x8 w = *reinterpret_cast<const bf16x8*>(
                wf1 + (((mt * 4 + ks) * 64 + lane) << 3));
            acc1[0][mt] = __builtin_amdgcn_mfma_f32_16x16x32_bf16(w, zf[0][ks], acc1[0][mt], 0, 0, 0);
            acc1[1][mt] = __builtin_amdgcn_mfma_f32_16x16x32_bf16(w, zf[1][ks], acc1[1][mt], 0, 0, 0);
        }

    // bias + relu + pack to bf16 pairs: P[s][mt][0] = cols(+0,+1), [1] = (+2,+3)
    unsigned P[2][8][2];
#pragma unroll
    for (int s = 0; s < 2; ++s)
#pragma unroll
        for (int mt = 0; mt < 8; ++mt) {
            float4 bv = *reinterpret_cast<const float4*>(bias1 + mt * 16 + hi * 4);
            float v0 = fmaxf(acc1[s][mt][0] + bv.x, 0.f);
            float v1 = fmaxf(acc1[s][mt][1] + bv.y, 0.f);
            float v2 = fmaxf(acc1[s][mt][2] + bv.z, 0.f);
            float v3 = fmaxf(acc1[s][mt][3] + bv.w, 0.f);
            P[s][mt][0] = cvtpk(v0, v1);
            P[s][mt][1] = cvtpk(v2, v3);
        }

    // register transpose -> B2-frags of z1^T:
    // target dword d of k-step ks comes from lane ((2hi+(d>>1))&3)*16+r,
    // reg P[2ks + (hi>>1)][d&1]
    const int srcA = ((2 * hi) & 3) * 16 + r;
    const int srcB = ((2 * hi + 1) & 3) * 16 + r;
    bf16x8 b2[2][4];
#pragma unroll
    for (int s = 0; s < 2; ++s)
#pragma unroll
        for (int ks = 0; ks < 4; ++ks) {
            unsigned dw[4];
#pragma unroll
            for (int d = 0; d < 4; ++d) {
                int sl = (d < 2) ? srcA : srcB;
                unsigned pa = (unsigned)__shfl((int)P[s][2 * ks][d & 1], sl);
                unsigned pb = (unsigned)__shfl((int)P[s][2 * ks + 1][d & 1], sl);
                dw[d] = (hi < 2) ? pa : pb;
            }
            union { unsigned u[4]; bf16x8 v; } cv;
            cv.u[0] = dw[0]; cv.u[1] = dw[1]; cv.u[2] = dw[2]; cv.u[3] = dw[3];
            b2[s][ks] = cv.v;
        }

    // matmul 2
    f32x4 acc2[2][8];
#pragma unroll
    for (int s = 0; s < 2; ++s)
#pragma unroll
        for (int mt = 0; mt < 8; ++mt) acc2[s][mt] = (f32x4){0.f, 0.f, 0.f, 0.f};
#pragma unroll
    for (int mt = 0; mt < 8; ++mt)
#pragma unroll
        for (int ks = 0; ks < 4; ++ks) {
            bf16x8 w = *reinterpret_cast<const bf16x8*>(
                wf2 + (((mt * 4 + ks) * 64 + lane) << 3));
            acc2[0][mt] = __builtin_amdgcn_mfma_f32_16x16x32_bf16(w, b2[0][ks], acc2[0][mt], 0, 0, 0);
            acc2[1][mt] = __builtin_amdgcn_mfma_f32_16x16x32_bf16(w, b2[1][ks], acc2[1][mt], 0, 0, 0);
        }

    // epilogue: bn + relu -> h (8B packed stores), pooled reduce + atomics
#pragma unroll
    for (int s = 0; s < 2; ++s) {
        const int row = rs[s] + r;
        int ga = gidx[rs[s]], gb = gidx[rs[s] + 15];
        bool uni = (ga == gb);
        int myg = uni ? ga : gidx[row];
#pragma unroll
        for (int mt = 0; mt < 8; ++mt) {
            int c0 = mt * 16 + hi * 4;
            float4 bv = *reinterpret_cast<const float4*>(bias2 + c0);
            float4 mv = *reinterpret_cast<const float4*>(mean + c0);
            float4 vv = *reinterpret_cast<const float4*>(var + c0);
            float4 gg = *reinterpret_cast<const float4*>(gamma + c0);
            float4 bt = *reinterpret_cast<const float4*>(beta + c0);
            float v0 = fmaxf((acc2[s][mt][0] + bv.x - mv.x) * (gg.x * rsqrtf(vv.x + 1e-3f)) + bt.x, 0.f);
            float v1 = fmaxf((acc2[s][mt][1] + bv.y - mv.y) * (gg.y * rsqrtf(vv.y + 1e-3f)) + bt.y, 0.f);
            float v2 = fmaxf((acc2[s][mt][2] + bv.z - mv.z) * (gg.z * rsqrtf(vv.z + 1e-3f)) + bt.z, 0.f);
            float v3 = fmaxf((acc2[s][mt][3] + bv.w - mv.w) * (gg.w * rsqrtf(vv.w + 1e-3f)) + bt.w, 0.f);
            if (valid[s]) {
                uint2 pk;
                pk.x = cvtpk(v0, v1);
                pk.y = cvtpk(v2, v3);
                *reinterpret_cast<uint2*>(outp + (size_t)row * U + c0) = pk;
            }
            if (uni) {
                float p0 = v0, p1 = v1, p2 = v2, p3 = v3;
#pragma unroll
                for (int m = 1; m <= 8; m <<= 1) {
                    p0 += __shfl_xor(p0, m);
                    p1 += __shfl_xor(p1, m);
                    p2 += __shfl_xor(p2, m);
                    p3 += __shfl_xor(p3, m);
                }
                if (valid[s] && r < 4) {
                    float pick = (r == 0) ? p0 : (r == 1) ? p1 : (r == 2) ? p2 : p3;
                    unsafeAtomicAdd(&pooled[(size_t)ga * (NGIN * U) + pool_off + c0 + r], pick);
                }
            } else if (valid[s]) {
                float* pp = &pooled[(size_t)myg * (NGIN * U) + pool_off + c0];
                unsafeAtomicAdd(pp + 0, v0);
                unsafeAtomicAdd(pp + 1, v1);
                unsafeAtomicAdd(pp + 2, v2);
                unsafeAtomicAdd(pp + 3, v3);
            }
        }
    }
}

// ---------------------------------------------------------------------------
// readout MLPs (fp32, tiny)
// ---------------------------------------------------------------------------
__global__ __launch_bounds__(128) void mlp1_k(const float* __restrict__ pooled,
                                              const float* __restrict__ Wm1,
                                              const float* __restrict__ bm1,
                                              float* __restrict__ g) {
    __shared__ float sp[NGIN * U];
    int gi = blockIdx.x, c = threadIdx.x;
    for (int j = c; j < NGIN * U; j += 128) sp[j] = pooled[(size_t)gi * (NGIN * U) + j];
    __syncthreads();
    float acc = bm1[c];
    for (int k = 0; k < NGIN * U; ++k) acc = fmaf(sp[k], Wm1[(size_t)k * 128 + c], acc);
    g[gi * 128 + c] = fmaxf(acc, 0.f);
}

__global__ __launch_bounds__(256) void mlp2_k(const float* __restrict__ g,
                                              const float* __restrict__ Wm2,
                                              const float* __restrict__ bm2,
                                              float* __restrict__ out) {
    int idx = blockIdx.x * 256 + threadIdx.x;
    int gi = idx >> 4, c = idx & 15;
    float acc = bm2[c];
    for (int k = 0; k < 128; ++k) acc = fmaf(g[gi * 128 + k], Wm2[k * 16 + c], acc);
    out[gi * 16 + c] = acc;
}

extern "C" void kernel_launch(void* const* d_in, const int* in_sizes, int n_in,
                              void* d_out, int out_size, void* d_ws, size_t ws_size,
                              hipStream_t stream) {
    const float* x   = (const float*)d_in[0];
    const int*   ei  = (const int*)d_in[1];
    const float* ew  = (const float*)d_in[2];
    const int*   gix = (const int*)d_in[3];
    const float* W1  = (const float*)d_in[4];
    const float* b1  = (const float*)d_in[5];
    const float* W2  = (const float*)d_in[6];
    const float* b2  = (const float*)d_in[7];
    const float* gam = (const float*)d_in[8];
    const float* bet = (const float*)d_in[9];
    const float* bmn = (const float*)d_in[10];
    const float* bvr = (const float*)d_in[11];
    const float* Wm1 = (const float*)d_in[12];
    const float* bm1 = (const float*)d_in[13];
    const float* Wm2 = (const float*)d_in[14];
    const float* bm2 = (const float*)d_in[15];
    float* out = (float*)d_out;

    unsigned short* hb = (unsigned short*)d_ws;
    unsigned short* z  = hb + (size_t)NN * U;
    float* pooled = (float*)(z + (size_t)NN * U);
    float* gbuf   = pooled + (size_t)NG * (NGIN * U);
    unsigned short* wfrag = (unsigned short*)(gbuf + (size_t)NG * 128);
    unsigned* esw = (unsigned*)(wfrag + 6 * 16384);
    uint2* tmp    = (uint2*)(esw + NE);
    int*   rowptr = (int*)(tmp + NE);
    int*   bcnt   = rowptr + (NN + 1);
    int*   bcur   = bcnt + NBUCK;
    int*   boff   = bcur + NBUCK;

    convert_k<<<(NN * U / 4 + 255) / 256, 256, 0, stream>>>(x, hb);
    hipMemsetAsync(bcnt, 0, NBUCK * sizeof(int), stream);
    bhist_k<<<NAB, 256, 0, stream>>>(ei, bcnt);
    bscan_k<<<1, 64, 0, stream>>>(bcnt, bcur, boff, rowptr);
    phaseA_k<<<NAB, 256, 0, stream>>>(ei, ew, bcur, tmp);
    phaseB_k<<<NBUCK, 256, 0, stream>>>(tmp, boff, rowptr, esw);
    wfrag_k<<<6, 256, 0, stream>>>(W1, W2, wfrag);
    hipMemsetAsync(pooled, 0, (size_t)NG * (NGIN * U) * sizeof(float), stream);

    const int dense_grid = (NN / 16 + 7) / 8;   // 4 waves x 2 strips x 16 rows
    for (int i = 0; i < NGIN; ++i) {
        gather_k<<<NN / 4, 256, 0, stream>>>(hb, esw, rowptr, z);
        fused_dense_k<<<dense_grid, 256, 0, stream>>>(
            z, wfrag + (size_t)(2 * i) * 16384, wfrag + (size_t)(2 * i + 1) * 16384,
            b1 + i * U, b2 + i * U,
            gam + i * U, bet + i * U, bmn + i * U, bvr + i * U,
            gix, hb, pooled, i * U);
    }
    mlp1_k<<<NG, 128, 0, stream>>>(pooled, Wm1, bm1, gbuf);
    mlp2_k<<<(NG * 16) / 256, 256, 0, stream>>>(gbuf, Wm2, bm2, out);
}

// Round 10
// 333.334 us; speedup vs baseline: 1.4194x; 1.4194x over previous
//
#include <hip/hip_runtime.h>

#define NN 100000
#define NE 800000
#define NG 128
#define U  128
#define NGIN 3
#define NBUCK 64
#define NPB 1563                 // ceil(NN / NBUCK)
#define ACHUNK 4096
#define NAB ((NE + ACHUNK - 1) / ACHUNK)   // 196 phase-A blocks

typedef short bf16x8 __attribute__((ext_vector_type(8)));
typedef float f32x4 __attribute__((ext_vector_type(4)));

__device__ __forceinline__ unsigned short f2b(float f) {
    union { float f; unsigned u; } v; v.f = f;
    unsigned r = v.u + 0x7FFF + ((v.u >> 16) & 1);   // RNE
    return (unsigned short)(r >> 16);
}
__device__ __forceinline__ float blo(unsigned u) {
    union { unsigned u; float f; } v; v.u = u << 16; return v.f;
}
__device__ __forceinline__ float bhi(unsigned u) {
    union { unsigned u; float f; } v; v.u = u & 0xffff0000u; return v.f;
}

// ---------------------------------------------------------------------------
// x (fp32) -> hb (bf16)
// ---------------------------------------------------------------------------
__global__ __launch_bounds__(256) void convert_k(const float* __restrict__ x,
                                                 unsigned short* __restrict__ hb) {
    int i = blockIdx.x * 256 + threadIdx.x;
    if (i >= NN * U / 4) return;
    float4 v = reinterpret_cast<const float4*>(x)[i];
    uint2 o;
    o.x = (unsigned)f2b(v.x) | ((unsigned)f2b(v.y) << 16);
    o.y = (unsigned)f2b(v.z) | ((unsigned)f2b(v.w) << 16);
    reinterpret_cast<uint2*>(hb)[i] = o;
}

// ---------------------------------------------------------------------------
// pack W (fp32 [k][c]) into MFMA B-fragment order (bf16)
// ---------------------------------------------------------------------------
__global__ __launch_bounds__(256) void wfrag_k(const float* __restrict__ W1,
                                               const float* __restrict__ W2,
                                               unsigned short* __restrict__ wfrag) {
    int b = blockIdx.x;
    const float* src = ((b & 1) ? W2 : W1) + (size_t)(b >> 1) * U * U;
    unsigned short* dst = wfrag + (size_t)b * 16384;
    for (int e = threadIdx.x; e < 16384; e += 256) {
        int j = e & 7, lane = (e >> 3) & 63, ks = (e >> 9) & 3, ct = e >> 11;
        int k = ks * 32 + ((lane >> 4) << 3) + j;
        int c = ct * 16 + (lane & 15);
        dst[e] = f2b(src[k * U + c]);
    }
}

// ---------------------------------------------------------------------------
// CSR build, owner-computes (bhist -> bscan -> phaseA -> phaseB)
// ---------------------------------------------------------------------------
__global__ __launch_bounds__(256) void bhist_k(const int* __restrict__ ei,
                                               int* __restrict__ bcnt) {
    __shared__ int lh[NBUCK];
    int tid = threadIdx.x;
    if (tid < NBUCK) lh[tid] = 0;
    __syncthreads();
    int e0 = blockIdx.x * ACHUNK;
    int eend = min(e0 + ACHUNK, NE);
    for (int e = e0 + tid; e < eend; e += 256)
        atomicAdd(&lh[ei[e] / NPB], 1);
    __syncthreads();
    if (tid < NBUCK && lh[tid]) atomicAdd(&bcnt[tid], lh[tid]);
}

__global__ __launch_bounds__(64) void bscan_k(const int* __restrict__ bcnt,
                                              int* __restrict__ bcur,
                                              int* __restrict__ boff,
                                              int* __restrict__ rowptr) {
    int lane = threadIdx.x;
    int v = bcnt[lane];
    int incl = v;
#pragma unroll
    for (int off = 1; off < 64; off <<= 1) {
        int n = __shfl_up(incl, off);
        if (lane >= off) incl += n;
    }
    int excl = incl - v;
    bcur[lane] = excl;
    boff[lane] = excl;
    if (lane == 63) { boff[64] = incl; rowptr[NN] = NE; }
}

__global__ __launch_bounds__(256) void phaseA_k(const int* __restrict__ ei,
                                                const float* __restrict__ ew,
                                                int* __restrict__ bcur,
                                                uint2* __restrict__ tmp) {
    __shared__ int lh[NBUCK];
    int tid = threadIdx.x;
    if (tid < NBUCK) lh[tid] = 0;
    __syncthreads();
    int e0 = blockIdx.x * ACHUNK;
    int eend = min(e0 + ACHUNK, NE);
    for (int e = e0 + tid; e < eend; e += 256)
        atomicAdd(&lh[ei[e] / NPB], 1);
    __syncthreads();
    if (tid < NBUCK) {
        int c = lh[tid];
        lh[tid] = c ? atomicAdd(&bcur[tid], c) : 0;
    }
    __syncthreads();
    for (int e = e0 + tid; e < eend; e += 256) {
        int d = ei[e];
        int pos = atomicAdd(&lh[d / NPB], 1);
        uint2 r;
        r.x = ((unsigned)ei[NE + e] << 15) | (unsigned)f2b(ew[e]);
        r.y = (unsigned)d;
        tmp[pos] = r;
    }
}

__global__ __launch_bounds__(256) void phaseB_k(const uint2* __restrict__ tmp,
                                                const int* __restrict__ boff,
                                                int* __restrict__ rowptr,
                                                unsigned* __restrict__ esw) {
    __shared__ int cnt[1792];
    __shared__ int ws[4];
    const int tid = threadIdx.x;
    const int b = blockIdx.x;
    const int n0 = b * NPB;
    const int npb = min(NPB, NN - n0);
    const int wbeg = boff[b], wend = boff[b + 1];

    for (int i = tid; i < 1792; i += 256) cnt[i] = 0;
    __syncthreads();
    for (int e = wbeg + tid; e < wend; e += 256)
        atomicAdd(&cnt[(int)tmp[e].y - n0], 1);
    __syncthreads();
    int base = tid * 7;
    int v[7]; int s = 0;
#pragma unroll
    for (int k = 0; k < 7; ++k) { v[k] = cnt[base + k]; s += v[k]; }
    int lane = tid & 63, wid = tid >> 6;
    int incl = s;
#pragma unroll
    for (int off = 1; off < 64; off <<= 1) {
        int n = __shfl_up(incl, off);
        if (lane >= off) incl += n;
    }
    if (lane == 63) ws[wid] = incl;
    __syncthreads();
    if (tid == 0) {
        int a = 0;
#pragma unroll
        for (int w = 0; w < 4; ++w) { int t = ws[w]; ws[w] = a; a += t; }
    }
    __syncthreads();
    int run = wbeg + ws[wid] + (incl - s);
#pragma unroll
    for (int k = 0; k < 7; ++k) { cnt[base + k] = run; run += v[k]; }
    __syncthreads();
    for (int i = tid; i < npb; i += 256) rowptr[n0 + i] = cnt[i];
    __syncthreads();
    for (int e = wbeg + tid; e < wend; e += 256) {
        uint2 r = tmp[e];
        int pos = atomicAdd(&cnt[(int)r.y - n0], 1);
        esw[pos] = r.x;
    }
}

// ---------------------------------------------------------------------------
// gather: z[n] = 1.5*h[n] + sum h[src]*w ; unroll x8, 8 row loads in flight
// ---------------------------------------------------------------------------
__global__ __launch_bounds__(256) void gather_k(const unsigned short* __restrict__ h,
                                                const unsigned* __restrict__ esw,
                                                const int* __restrict__ rowptr,
                                                unsigned short* __restrict__ z) {
    int node = blockIdx.x * 4 + (threadIdx.x >> 6);
    if (node >= NN) return;
    int lane = threadIdx.x & 63;
    const unsigned* hp = reinterpret_cast<const unsigned*>(h);
    int beg = rowptr[node], end = rowptr[node + 1];

    float ax[8], ay[8];
#pragma unroll
    for (int k = 0; k < 8; ++k) { ax[k] = 0.f; ay[k] = 0.f; }

    for (int cb = beg; cb < end; cb += 64) {
        int n = min(end - cb, 64);
        unsigned rec = (lane < n) ? esw[cb + lane] : 0u;   // pad: src 0, w +0.0
        int sv = (int)(rec >> 15);
        float wv = __uint_as_float((rec & 0x7FFFu) << 16);
        for (int i = 0; i < n; i += 8) {
            int s_[8]; float w_[8]; unsigned h_[8];
#pragma unroll
            for (int k = 0; k < 8; ++k) {
                s_[k] = __shfl(sv, i + k);
                w_[k] = __shfl(wv, i + k);
            }
#pragma unroll
            for (int k = 0; k < 8; ++k)
                h_[k] = hp[(size_t)s_[k] * 64 + lane];
#pragma unroll
            for (int k = 0; k < 8; ++k) {
                ax[k] = fmaf(blo(h_[k]), w_[k], ax[k]);
                ay[k] = fmaf(bhi(h_[k]), w_[k], ay[k]);
            }
        }
    }
    float axs = ((ax[0] + ax[1]) + (ax[2] + ax[3])) + ((ax[4] + ax[5]) + (ax[6] + ax[7]));
    float ays = ((ay[0] + ay[1]) + (ay[2] + ay[3])) + ((ay[4] + ay[5]) + (ay[6] + ay[7]));
    unsigned hn = hp[(size_t)node * 64 + lane];
    axs = fmaf(1.5f, blo(hn), axs);
    ays = fmaf(1.5f, bhi(hn), ays);
    reinterpret_cast<unsigned*>(z)[(size_t)node * 64 + lane] =
        (unsigned)f2b(axs) | ((unsigned)f2b(ays) << 16);
}

// ---------------------------------------------------------------------------
// fused per-layer dense: h = relu(bn(relu(z@W1+b1)@W2+b2)) + pooled atomics
// ONE 16-row strip per wave (max TLP); z1 passes through WAVE-PRIVATE LDS
// (chunk-major: writes scattered b16, reads conflict-free b128).
// No __syncthreads — wave-local s_waitcnt lgkmcnt(0) orders write->read.
// ---------------------------------------------------------------------------
__global__ __launch_bounds__(256) void fused_dense_k(const unsigned short* __restrict__ A,
                                                     const unsigned short* __restrict__ wf1,
                                                     const unsigned short* __restrict__ wf2,
                                                     const float* __restrict__ bias1,
                                                     const float* __restrict__ bias2,
                                                     const float* __restrict__ gamma,
                                                     const float* __restrict__ beta,
                                                     const float* __restrict__ mean,
                                                     const float* __restrict__ var,
                                                     const int* __restrict__ gidx,
                                                     unsigned short* __restrict__ outp,
                                                     float* __restrict__ pooled,
                                                     int pool_off) {
    __shared__ unsigned short lds[4 * 2048];   // 4 waves x 4KB (wave-private tiles)
    const int lane = threadIdx.x & 63;
    const int wid = threadIdx.x >> 6;
    const int strip = blockIdx.x * 4 + wid;
    const int r0t = strip * 16;
    const bool valid = (r0t < NN);
    const int r0 = valid ? r0t : 0;
    unsigned short* myl = lds + wid * 2048;

    const int c = lane & 15;
    const int g = lane >> 4;

    // ---- matmul 1: z1 = relu(A @ W1 + b1) ----
    bf16x8 a[4];
    const size_t abase = (size_t)(r0 + c) * U + (g << 3);
#pragma unroll
    for (int ks = 0; ks < 4; ++ks)
        a[ks] = *reinterpret_cast<const bf16x8*>(A + abase + ks * 32);

    f32x4 acc1[8];
#pragma unroll
    for (int ct = 0; ct < 8; ++ct) acc1[ct] = (f32x4){0.f, 0.f, 0.f, 0.f};
#pragma unroll
    for (int ct = 0; ct < 8; ++ct)
#pragma unroll
        for (int ks = 0; ks < 4; ++ks) {
            bf16x8 b = *reinterpret_cast<const bf16x8*>(
                wf1 + (((ct * 4 + ks) * 64 + lane) << 3));
            acc1[ct] = __builtin_amdgcn_mfma_f32_16x16x32_bf16(a[ks], b, acc1[ct], 0, 0, 0);
        }

    // epilogue 1 -> wave-private LDS (chunk-major): idx = chunk*128 + row*8 + within
#pragma unroll
    for (int ct = 0; ct < 8; ++ct) {
        int col = ct * 16 + c;
        float bv = bias1[col];
        int chunk = col >> 3, within = col & 7;
#pragma unroll
        for (int j = 0; j < 4; ++j) {
            int row = (g << 2) + j;
            float v = fmaxf(acc1[ct][j] + bv, 0.f);
            myl[chunk * 128 + row * 8 + within] = f2b(v);
        }
    }
    // wave-local ordering: drain DS writes before DS reads (no block barrier)
    asm volatile("s_waitcnt lgkmcnt(0)" ::: "memory");

    // ---- matmul 2: A2-frags from LDS (conflict-free b128) ----
    bf16x8 a2[4];
#pragma unroll
    for (int ks = 0; ks < 4; ++ks)
        a2[ks] = *reinterpret_cast<const bf16x8*>(myl + (ks * 4 + g) * 128 + c * 8);

    f32x4 acc2[8];
#pragma unroll
    for (int ct = 0; ct < 8; ++ct) acc2[ct] = (f32x4){0.f, 0.f, 0.f, 0.f};
#pragma unroll
    for (int ct = 0; ct < 8; ++ct)
#pragma unroll
        for (int ks = 0; ks < 4; ++ks) {
            bf16x8 b = *reinterpret_cast<const bf16x8*>(
                wf2 + (((ct * 4 + ks) * 64 + lane) << 3));
            acc2[ct] = __builtin_amdgcn_mfma_f32_16x16x32_bf16(a2[ks], b, acc2[ct], 0, 0, 0);
        }

    // ---- epilogue 2: bn + relu -> outp, pooled atomics ----
    const int rbase = r0 + (g << 2);
    int ga = gidx[r0], gb = gidx[r0 + 15];
    bool uni = (ga == gb);
#pragma unroll
    for (int ct = 0; ct < 8; ++ct) {
        int col = ct * 16 + c;
        float bv = bias2[col];
        float scl = gamma[col] * rsqrtf(var[col] + 1e-3f);
        float mv = mean[col], bt = beta[col];
        float hv[4];
        float psum = 0.f;
#pragma unroll
        for (int j = 0; j < 4; ++j) {
            float v = fmaxf((acc2[ct][j] + bv - mv) * scl + bt, 0.f);
            hv[j] = v;
            psum += v;
            if (valid) outp[(size_t)(rbase + j) * U + col] = f2b(v);
        }
        if (uni) {
            psum += __shfl_xor(psum, 16);
            psum += __shfl_xor(psum, 32);
            if (valid && lane < 16)
                unsafeAtomicAdd(&pooled[(size_t)ga * (NGIN * U) + pool_off + col], psum);
        } else if (valid) {
#pragma unroll
            for (int j = 0; j < 4; ++j)
                unsafeAtomicAdd(&pooled[(size_t)gidx[rbase + j] * (NGIN * U) + pool_off + col], hv[j]);
        }
    }
}

// ---------------------------------------------------------------------------
// readout MLPs (fp32, tiny)
// ---------------------------------------------------------------------------
__global__ __launch_bounds__(128) void mlp1_k(const float* __restrict__ pooled,
                                              const float* __restrict__ Wm1,
                                              const float* __restrict__ bm1,
                                              float* __restrict__ g) {
    __shared__ float sp[NGIN * U];
    int gi = blockIdx.x, c = threadIdx.x;
    for (int j = c; j < NGIN * U; j += 128) sp[j] = pooled[(size_t)gi * (NGIN * U) + j];
    __syncthreads();
    float acc = bm1[c];
    for (int k = 0; k < NGIN * U; ++k) acc = fmaf(sp[k], Wm1[(size_t)k * 128 + c], acc);
    g[gi * 128 + c] = fmaxf(acc, 0.f);
}

__global__ __launch_bounds__(256) void mlp2_k(const float* __restrict__ g,
                                              const float* __restrict__ Wm2,
                                              const float* __restrict__ bm2,
                                              float* __restrict__ out) {
    int idx = blockIdx.x * 256 + threadIdx.x;
    int gi = idx >> 4, c = idx & 15;
    float acc = bm2[c];
    for (int k = 0; k < 128; ++k) acc = fmaf(g[gi * 128 + k], Wm2[k * 16 + c], acc);
    out[gi * 16 + c] = acc;
}

extern "C" void kernel_launch(void* const* d_in, const int* in_sizes, int n_in,
                              void* d_out, int out_size, void* d_ws, size_t ws_size,
                              hipStream_t stream) {
    const float* x   = (const float*)d_in[0];
    const int*   ei  = (const int*)d_in[1];
    const float* ew  = (const float*)d_in[2];
    const int*   gix = (const int*)d_in[3];
    const float* W1  = (const float*)d_in[4];
    const float* b1  = (const float*)d_in[5];
    const float* W2  = (const float*)d_in[6];
    const float* b2  = (const float*)d_in[7];
    const float* gam = (const float*)d_in[8];
    const float* bet = (const float*)d_in[9];
    const float* bmn = (const float*)d_in[10];
    const float* bvr = (const float*)d_in[11];
    const float* Wm1 = (const float*)d_in[12];
    const float* bm1 = (const float*)d_in[13];
    const float* Wm2 = (const float*)d_in[14];
    const float* bm2 = (const float*)d_in[15];
    float* out = (float*)d_out;

    unsigned short* hb = (unsigned short*)d_ws;
    unsigned short* z  = hb + (size_t)NN * U;
    float* pooled = (float*)(z + (size_t)NN * U);
    float* gbuf   = pooled + (size_t)NG * (NGIN * U);
    unsigned short* wfrag = (unsigned short*)(gbuf + (size_t)NG * 128);
    unsigned* esw = (unsigned*)(wfrag + 6 * 16384);
    uint2* tmp    = (uint2*)(esw + NE);
    int*   rowptr = (int*)(tmp + NE);
    int*   bcnt   = rowptr + (NN + 1);
    int*   bcur   = bcnt + NBUCK;
    int*   boff   = bcur + NBUCK;

    convert_k<<<(NN * U / 4 + 255) / 256, 256, 0, stream>>>(x, hb);
    hipMemsetAsync(bcnt, 0, NBUCK * sizeof(int), stream);
    bhist_k<<<NAB, 256, 0, stream>>>(ei, bcnt);
    bscan_k<<<1, 64, 0, stream>>>(bcnt, bcur, boff, rowptr);
    phaseA_k<<<NAB, 256, 0, stream>>>(ei, ew, bcur, tmp);
    phaseB_k<<<NBUCK, 256, 0, stream>>>(tmp, boff, rowptr, esw);
    wfrag_k<<<6, 256, 0, stream>>>(W1, W2, wfrag);
    hipMemsetAsync(pooled, 0, (size_t)NG * (NGIN * U) * sizeof(float), stream);

    const int dense_grid = (NN / 16 + 3) / 4;   // 1 strip per wave, 4 waves/block
    for (int i = 0; i < NGIN; ++i) {
        gather_k<<<NN / 4, 256, 0, stream>>>(hb, esw, rowptr, z);
        fused_dense_k<<<dense_grid, 256, 0, stream>>>(
            z, wfrag + (size_t)(2 * i) * 16384, wfrag + (size_t)(2 * i + 1) * 16384,
            b1 + i * U, b2 + i * U,
            gam + i * U, bet + i * U, bmn + i * U, bvr + i * U,
            gix, hb, pooled, i * U);
    }
    mlp1_k<<<NG, 128, 0, stream>>>(pooled, Wm1, bm1, gbuf);
    mlp2_k<<<(NG * 16) / 256, 256, 0, stream>>>(gbuf, Wm2, bm2, out);
}

// Round 11
// 330.277 us; speedup vs baseline: 1.4325x; 1.0093x over previous
//
#include <hip/hip_runtime.h>

#define NN 100000
#define NE 800000
#define NG 128
#define U  128
#define NGIN 3
#define NBUCK 64
#define NPB 1563                 // ceil(NN / NBUCK)
#define ACHUNK 4096
#define NAB ((NE + ACHUNK - 1) / ACHUNK)   // 196 phase-A blocks

typedef short bf16x8 __attribute__((ext_vector_type(8)));
typedef float f32x4 __attribute__((ext_vector_type(4)));

__device__ __forceinline__ unsigned short f2b(float f) {
    union { float f; unsigned u; } v; v.f = f;
    unsigned r = v.u + 0x7FFF + ((v.u >> 16) & 1);   // RNE
    return (unsigned short)(r >> 16);
}
__device__ __forceinline__ float blo(unsigned u) {
    union { unsigned u; float f; } v; v.u = u << 16; return v.f;
}
__device__ __forceinline__ float bhi(unsigned u) {
    union { unsigned u; float f; } v; v.u = u & 0xffff0000u; return v.f;
}

// ---------------------------------------------------------------------------
// x (fp32) -> hb (bf16)
// ---------------------------------------------------------------------------
__global__ __launch_bounds__(256) void convert_k(const float* __restrict__ x,
                                                 unsigned short* __restrict__ hb) {
    int i = blockIdx.x * 256 + threadIdx.x;
    if (i >= NN * U / 4) return;
    float4 v = reinterpret_cast<const float4*>(x)[i];
    uint2 o;
    o.x = (unsigned)f2b(v.x) | ((unsigned)f2b(v.y) << 16);
    o.y = (unsigned)f2b(v.z) | ((unsigned)f2b(v.w) << 16);
    reinterpret_cast<uint2*>(hb)[i] = o;
}

// ---------------------------------------------------------------------------
// pack W (fp32 [k][c]) into MFMA B-fragment order (bf16)
// ---------------------------------------------------------------------------
__global__ __launch_bounds__(256) void wfrag_k(const float* __restrict__ W1,
                                               const float* __restrict__ W2,
                                               unsigned short* __restrict__ wfrag) {
    int b = blockIdx.x;
    const float* src = ((b & 1) ? W2 : W1) + (size_t)(b >> 1) * U * U;
    unsigned short* dst = wfrag + (size_t)b * 16384;
    for (int e = threadIdx.x; e < 16384; e += 256) {
        int j = e & 7, lane = (e >> 3) & 63, ks = (e >> 9) & 3, ct = e >> 11;
        int k = ks * 32 + ((lane >> 4) << 3) + j;
        int c = ct * 16 + (lane & 15);
        dst[e] = f2b(src[k * U + c]);
    }
}

// bn epilogue precompute: scl = gamma*rsqrt(var+eps); sh = (b2-mean)*scl+beta
__global__ __launch_bounds__(128) void bnprep_k(const float* __restrict__ b2,
                                                const float* __restrict__ gam,
                                                const float* __restrict__ bet,
                                                const float* __restrict__ mean,
                                                const float* __restrict__ var,
                                                float* __restrict__ scl,
                                                float* __restrict__ sh) {
    int i = blockIdx.x * 128 + threadIdx.x;   // layer*128 + col
    float s = gam[i] * rsqrtf(var[i] + 1e-3f);
    scl[i] = s;
    sh[i] = (b2[i] - mean[i]) * s + bet[i];
}

// ---------------------------------------------------------------------------
// CSR build, owner-computes (bhist -> bscan -> phaseA -> phaseB)
// ---------------------------------------------------------------------------
__global__ __launch_bounds__(256) void bhist_k(const int* __restrict__ ei,
                                               int* __restrict__ bcnt) {
    __shared__ int lh[NBUCK];
    int tid = threadIdx.x;
    if (tid < NBUCK) lh[tid] = 0;
    __syncthreads();
    int e0 = blockIdx.x * ACHUNK;
    int eend = min(e0 + ACHUNK, NE);
    for (int e = e0 + tid; e < eend; e += 256)
        atomicAdd(&lh[ei[e] / NPB], 1);
    __syncthreads();
    if (tid < NBUCK && lh[tid]) atomicAdd(&bcnt[tid], lh[tid]);
}

__global__ __launch_bounds__(64) void bscan_k(const int* __restrict__ bcnt,
                                              int* __restrict__ bcur,
                                              int* __restrict__ boff,
                                              int* __restrict__ rowptr) {
    int lane = threadIdx.x;
    int v = bcnt[lane];
    int incl = v;
#pragma unroll
    for (int off = 1; off < 64; off <<= 1) {
        int n = __shfl_up(incl, off);
        if (lane >= off) incl += n;
    }
    int excl = incl - v;
    bcur[lane] = excl;
    boff[lane] = excl;
    if (lane == 63) { boff[64] = incl; rowptr[NN] = NE; }
}

__global__ __launch_bounds__(256) void phaseA_k(const int* __restrict__ ei,
                                                const float* __restrict__ ew,
                                                int* __restrict__ bcur,
                                                uint2* __restrict__ tmp) {
    __shared__ int lh[NBUCK];
    int tid = threadIdx.x;
    if (tid < NBUCK) lh[tid] = 0;
    __syncthreads();
    int e0 = blockIdx.x * ACHUNK;
    int eend = min(e0 + ACHUNK, NE);
    for (int e = e0 + tid; e < eend; e += 256)
        atomicAdd(&lh[ei[e] / NPB], 1);
    __syncthreads();
    if (tid < NBUCK) {
        int c = lh[tid];
        lh[tid] = c ? atomicAdd(&bcur[tid], c) : 0;
    }
    __syncthreads();
    for (int e = e0 + tid; e < eend; e += 256) {
        int d = ei[e];
        int pos = atomicAdd(&lh[d / NPB], 1);
        uint2 r;
        r.x = ((unsigned)ei[NE + e] << 15) | (unsigned)f2b(ew[e]);
        r.y = (unsigned)d;
        tmp[pos] = r;
    }
}

__global__ __launch_bounds__(256) void phaseB_k(const uint2* __restrict__ tmp,
                                                const int* __restrict__ boff,
                                                int* __restrict__ rowptr,
                                                unsigned* __restrict__ esw) {
    __shared__ int cnt[1792];
    __shared__ int ws[4];
    const int tid = threadIdx.x;
    const int b = blockIdx.x;
    const int n0 = b * NPB;
    const int npb = min(NPB, NN - n0);
    const int wbeg = boff[b], wend = boff[b + 1];

    for (int i = tid; i < 1792; i += 256) cnt[i] = 0;
    __syncthreads();
    for (int e = wbeg + tid; e < wend; e += 256)
        atomicAdd(&cnt[(int)tmp[e].y - n0], 1);
    __syncthreads();
    int base = tid * 7;
    int v[7]; int s = 0;
#pragma unroll
    for (int k = 0; k < 7; ++k) { v[k] = cnt[base + k]; s += v[k]; }
    int lane = tid & 63, wid = tid >> 6;
    int incl = s;
#pragma unroll
    for (int off = 1; off < 64; off <<= 1) {
        int n = __shfl_up(incl, off);
        if (lane >= off) incl += n;
    }
    if (lane == 63) ws[wid] = incl;
    __syncthreads();
    if (tid == 0) {
        int a = 0;
#pragma unroll
        for (int w = 0; w < 4; ++w) { int t = ws[w]; ws[w] = a; a += t; }
    }
    __syncthreads();
    int run = wbeg + ws[wid] + (incl - s);
#pragma unroll
    for (int k = 0; k < 7; ++k) { cnt[base + k] = run; run += v[k]; }
    __syncthreads();
    for (int i = tid; i < npb; i += 256) rowptr[n0 + i] = cnt[i];
    __syncthreads();
    for (int e = wbeg + tid; e < wend; e += 256) {
        uint2 r = tmp[e];
        int pos = atomicAdd(&cnt[(int)r.y - n0], 1);
        esw[pos] = r.x;
    }
}

// ---------------------------------------------------------------------------
// gather: z[n] = 1.5*h[n] + sum h[src]*w ; unroll x8, 8 row loads in flight
// ---------------------------------------------------------------------------
__global__ __launch_bounds__(256) void gather_k(const unsigned short* __restrict__ h,
                                                const unsigned* __restrict__ esw,
                                                const int* __restrict__ rowptr,
                                                unsigned short* __restrict__ z) {
    int node = blockIdx.x * 4 + (threadIdx.x >> 6);
    if (node >= NN) return;
    int lane = threadIdx.x & 63;
    const unsigned* hp = reinterpret_cast<const unsigned*>(h);
    int beg = rowptr[node], end = rowptr[node + 1];

    float ax[8], ay[8];
#pragma unroll
    for (int k = 0; k < 8; ++k) { ax[k] = 0.f; ay[k] = 0.f; }

    for (int cb = beg; cb < end; cb += 64) {
        int n = min(end - cb, 64);
        unsigned rec = (lane < n) ? esw[cb + lane] : 0u;   // pad: src 0, w +0.0
        int sv = (int)(rec >> 15);
        float wv = __uint_as_float((rec & 0x7FFFu) << 16);
        for (int i = 0; i < n; i += 8) {
            int s_[8]; float w_[8]; unsigned h_[8];
#pragma unroll
            for (int k = 0; k < 8; ++k) {
                s_[k] = __shfl(sv, i + k);
                w_[k] = __shfl(wv, i + k);
            }
#pragma unroll
            for (int k = 0; k < 8; ++k)
                h_[k] = hp[(size_t)s_[k] * 64 + lane];
#pragma unroll
            for (int k = 0; k < 8; ++k) {
                ax[k] = fmaf(blo(h_[k]), w_[k], ax[k]);
                ay[k] = fmaf(bhi(h_[k]), w_[k], ay[k]);
            }
        }
    }
    float axs = ((ax[0] + ax[1]) + (ax[2] + ax[3])) + ((ax[4] + ax[5]) + (ax[6] + ax[7]));
    float ays = ((ay[0] + ay[1]) + (ay[2] + ay[3])) + ((ay[4] + ay[5]) + (ay[6] + ay[7]));
    unsigned hn = hp[(size_t)node * 64 + lane];
    axs = fmaf(1.5f, blo(hn), axs);
    ays = fmaf(1.5f, bhi(hn), ays);
    reinterpret_cast<unsigned*>(z)[(size_t)node * 64 + lane] =
        (unsigned)f2b(axs) | ((unsigned)f2b(ays) << 16);
}

// ---------------------------------------------------------------------------
// fused per-layer dense with LDS-STAGED WEIGHTS:
//   stage wf1 -> LDS; m1 (B from LDS, 2 strips/wave); z1 -> LDS tiles;
//   re-stage wf2; m2; bn-precomputed epilogue + pooled atomics.
// LDS = 32KB weights + 32KB z1 tiles = 64KB (2 blocks/CU).
// ---------------------------------------------------------------------------
__global__ __launch_bounds__(256) void fused_dense_k(const unsigned short* __restrict__ A,
                                                     const unsigned short* __restrict__ wf1,
                                                     const unsigned short* __restrict__ wf2,
                                                     const float* __restrict__ bias1,
                                                     const float* __restrict__ sclp,
                                                     const float* __restrict__ shp,
                                                     const int* __restrict__ gidx,
                                                     unsigned short* __restrict__ outp,
                                                     float* __restrict__ pooled,
                                                     int pool_off) {
    __shared__ unsigned short swf[16384];      // 32KB staged weight table
    __shared__ unsigned short z1t[8][2048];    // 32KB z1 tiles (8 strips)
    const int tid = threadIdx.x;
    const int lane = tid & 63;
    const int wid = tid >> 6;
    const int c = lane & 15;
    const int g = lane >> 4;

    bool valid[2]; int rs[2];
#pragma unroll
    for (int s = 0; s < 2; ++s) {
        int sidx = blockIdx.x * 8 + wid * 2 + s;
        valid[s] = (sidx * 16 < NN);
        rs[s] = valid[s] ? sidx * 16 : 0;
    }

    // ---- stage wf1 ----
    {
        const uint4* wsrc = reinterpret_cast<const uint4*>(wf1);
        uint4* wdst = reinterpret_cast<uint4*>(swf);
#pragma unroll
        for (int i = 0; i < 8; ++i) wdst[tid + i * 256] = wsrc[tid + i * 256];
    }

    // A-frags (global; overlaps with staging)
    bf16x8 a[2][4];
#pragma unroll
    for (int s = 0; s < 2; ++s) {
        const size_t abase = (size_t)(rs[s] + c) * U + (g << 3);
#pragma unroll
        for (int ks = 0; ks < 4; ++ks)
            a[s][ks] = *reinterpret_cast<const bf16x8*>(A + abase + ks * 32);
    }
    __syncthreads();

    // ---- matmul 1: z1 = relu(A @ W1 + b1) ----
    f32x4 acc1[2][8];
#pragma unroll
    for (int s = 0; s < 2; ++s)
#pragma unroll
        for (int ct = 0; ct < 8; ++ct) acc1[s][ct] = (f32x4){0.f, 0.f, 0.f, 0.f};
#pragma unroll
    for (int ct = 0; ct < 8; ++ct)
#pragma unroll
        for (int ks = 0; ks < 4; ++ks) {
            bf16x8 b = *reinterpret_cast<const bf16x8*>(
                swf + (((ct * 4 + ks) * 64 + lane) << 3));
            acc1[0][ct] = __builtin_amdgcn_mfma_f32_16x16x32_bf16(a[0][ks], b, acc1[0][ct], 0, 0, 0);
            acc1[1][ct] = __builtin_amdgcn_mfma_f32_16x16x32_bf16(a[1][ks], b, acc1[1][ct], 0, 0, 0);
        }

    // ep1 -> z1 tiles (chunk-major: idx = chunk*128 + row*8 + within)
#pragma unroll
    for (int s = 0; s < 2; ++s) {
        unsigned short* myl = z1t[wid * 2 + s];
#pragma unroll
        for (int ct = 0; ct < 8; ++ct) {
            int col = ct * 16 + c;
            float bv = bias1[col];
            int chunk = col >> 3, within = col & 7;
#pragma unroll
            for (int j = 0; j < 4; ++j) {
                int row = (g << 2) + j;
                float v = fmaxf(acc1[s][ct][j] + bv, 0.f);
                myl[chunk * 128 + row * 8 + within] = f2b(v);
            }
        }
    }
    __syncthreads();

    // ---- re-stage wf2 over swf ----
    {
        const uint4* wsrc = reinterpret_cast<const uint4*>(wf2);
        uint4* wdst = reinterpret_cast<uint4*>(swf);
#pragma unroll
        for (int i = 0; i < 8; ++i) wdst[tid + i * 256] = wsrc[tid + i * 256];
    }
    __syncthreads();

    // ---- matmul 2 ----
    bf16x8 a2[2][4];
#pragma unroll
    for (int s = 0; s < 2; ++s) {
        unsigned short* myl = z1t[wid * 2 + s];
#pragma unroll
        for (int ks = 0; ks < 4; ++ks)
            a2[s][ks] = *reinterpret_cast<const bf16x8*>(myl + (ks * 4 + g) * 128 + c * 8);
    }

    f32x4 acc2[2][8];
#pragma unroll
    for (int s = 0; s < 2; ++s)
#pragma unroll
        for (int ct = 0; ct < 8; ++ct) acc2[s][ct] = (f32x4){0.f, 0.f, 0.f, 0.f};
#pragma unroll
    for (int ct = 0; ct < 8; ++ct)
#pragma unroll
        for (int ks = 0; ks < 4; ++ks) {
            bf16x8 b = *reinterpret_cast<const bf16x8*>(
                swf + (((ct * 4 + ks) * 64 + lane) << 3));
            acc2[0][ct] = __builtin_amdgcn_mfma_f32_16x16x32_bf16(a2[0][ks], b, acc2[0][ct], 0, 0, 0);
            acc2[1][ct] = __builtin_amdgcn_mfma_f32_16x16x32_bf16(a2[1][ks], b, acc2[1][ct], 0, 0, 0);
        }

    // ---- epilogue 2: v = relu(acc*scl + sh) -> outp, pooled atomics ----
#pragma unroll
    for (int s = 0; s < 2; ++s) {
        const int rbase = rs[s] + (g << 2);
        int ga = gidx[rs[s]], gb = gidx[rs[s] + 15];
        bool uni = (ga == gb);
#pragma unroll
        for (int ct = 0; ct < 8; ++ct) {
            int col = ct * 16 + c;
            float scl = sclp[col], sh = shp[col];
            float hv[4];
            float psum = 0.f;
#pragma unroll
            for (int j = 0; j < 4; ++j) {
                float v = fmaxf(fmaf(acc2[s][ct][j], scl, sh), 0.f);
                hv[j] = v;
                psum += v;
                if (valid[s]) outp[(size_t)(rbase + j) * U + col] = f2b(v);
            }
            if (uni) {
                psum += __shfl_xor(psum, 16);
                psum += __shfl_xor(psum, 32);
                if (valid[s] && lane < 16)
                    unsafeAtomicAdd(&pooled[(size_t)ga * (NGIN * U) + pool_off + col], psum);
            } else if (valid[s]) {
#pragma unroll
                for (int j = 0; j < 4; ++j)
                    unsafeAtomicAdd(&pooled[(size_t)gidx[rbase + j] * (NGIN * U) + pool_off + col], hv[j]);
            }
        }
    }
}

// ---------------------------------------------------------------------------
// readout MLPs (fp32, tiny)
// ---------------------------------------------------------------------------
__global__ __launch_bounds__(128) void mlp1_k(const float* __restrict__ pooled,
                                              const float* __restrict__ Wm1,
                                              const float* __restrict__ bm1,
                                              float* __restrict__ g) {
    __shared__ float sp[NGIN * U];
    int gi = blockIdx.x, c = threadIdx.x;
    for (int j = c; j < NGIN * U; j += 128) sp[j] = pooled[(size_t)gi * (NGIN * U) + j];
    __syncthreads();
    float acc = bm1[c];
    for (int k = 0; k < NGIN * U; ++k) acc = fmaf(sp[k], Wm1[(size_t)k * 128 + c], acc);
    g[gi * 128 + c] = fmaxf(acc, 0.f);
}

__global__ __launch_bounds__(256) void mlp2_k(const float* __restrict__ g,
                                              const float* __restrict__ Wm2,
                                              const float* __restrict__ bm2,
                                              float* __restrict__ out) {
    int idx = blockIdx.x * 256 + threadIdx.x;
    int gi = idx >> 4, c = idx & 15;
    float acc = bm2[c];
    for (int k = 0; k < 128; ++k) acc = fmaf(g[gi * 128 + k], Wm2[k * 16 + c], acc);
    out[gi * 16 + c] = acc;
}

extern "C" void kernel_launch(void* const* d_in, const int* in_sizes, int n_in,
                              void* d_out, int out_size, void* d_ws, size_t ws_size,
                              hipStream_t stream) {
    const float* x   = (const float*)d_in[0];
    const int*   ei  = (const int*)d_in[1];
    const float* ew  = (const float*)d_in[2];
    const int*   gix = (const int*)d_in[3];
    const float* W1  = (const float*)d_in[4];
    const float* b1  = (const float*)d_in[5];
    const float* W2  = (const float*)d_in[6];
    const float* b2  = (const float*)d_in[7];
    const float* gam = (const float*)d_in[8];
    const float* bet = (const float*)d_in[9];
    const float* bmn = (const float*)d_in[10];
    const float* bvr = (const float*)d_in[11];
    const float* Wm1 = (const float*)d_in[12];
    const float* bm1 = (const float*)d_in[13];
    const float* Wm2 = (const float*)d_in[14];
    const float* bm2 = (const float*)d_in[15];
    float* out = (float*)d_out;

    unsigned short* hb = (unsigned short*)d_ws;
    unsigned short* z  = hb + (size_t)NN * U;
    float* pooled = (float*)(z + (size_t)NN * U);
    float* gbuf   = pooled + (size_t)NG * (NGIN * U);
    unsigned short* wfrag = (unsigned short*)(gbuf + (size_t)NG * 128);
    unsigned* esw = (unsigned*)(wfrag + 6 * 16384);
    uint2* tmp    = (uint2*)(esw + NE);
    int*   rowptr = (int*)(tmp + NE);
    int*   bcnt   = rowptr + (NN + 1);
    int*   bcur   = bcnt + NBUCK;
    int*   boff   = bcur + NBUCK;
    float* sclp   = (float*)(boff + NBUCK + 1);
    float* shp    = sclp + NGIN * U;

    convert_k<<<(NN * U / 4 + 255) / 256, 256, 0, stream>>>(x, hb);
    hipMemsetAsync(bcnt, 0, NBUCK * sizeof(int), stream);
    bhist_k<<<NAB, 256, 0, stream>>>(ei, bcnt);
    bscan_k<<<1, 64, 0, stream>>>(bcnt, bcur, boff, rowptr);
    phaseA_k<<<NAB, 256, 0, stream>>>(ei, ew, bcur, tmp);
    phaseB_k<<<NBUCK, 256, 0, stream>>>(tmp, boff, rowptr, esw);
    wfrag_k<<<6, 256, 0, stream>>>(W1, W2, wfrag);
    bnprep_k<<<NGIN, 128, 0, stream>>>(b2, gam, bet, bmn, bvr, sclp, shp);
    hipMemsetAsync(pooled, 0, (size_t)NG * (NGIN * U) * sizeof(float), stream);

    const int dense_grid = (NN / 16 + 7) / 8;   // 4 waves x 2 strips x 16 rows
    for (int i = 0; i < NGIN; ++i) {
        gather_k<<<NN / 4, 256, 0, stream>>>(hb, esw, rowptr, z);
        fused_dense_k<<<dense_grid, 256, 0, stream>>>(
            z, wfrag + (size_t)(2 * i) * 16384, wfrag + (size_t)(2 * i + 1) * 16384,
            b1 + i * U, sclp + i * U, shp + i * U,
            gix, hb, pooled, i * U);
    }
    mlp1_k<<<NG, 128, 0, stream>>>(pooled, Wm1, bm1, gbuf);
    mlp2_k<<<(NG * 16) / 256, 256, 0, stream>>>(gbuf, Wm2, bm2, out);
}